// Round 23
// baseline (481.568 us; speedup 1.0000x reference)
//
#include <hip/hip_runtime.h>
#include <hip/hip_fp16.h>
#include <math.h>

// Problem constants: B=8, Tt=16, C=1, H=W=512, 4 in-channels, 10 T-planes.
#define Bd 8
#define Td 16
#define Hd 512
#define Wd 512
#define HWc (Hd * Wd)          // 262144
#define NPIX (Bd * HWc)        // 2,097,152

// ---------------- conv tiling: 16x16 tile, 1 px/thread, 256 threads ----------
#define CT  16
#define CR  18
#define CP  20
#define CTH2 256

// ---------------- single fused kernel (r22 proven): fp32 col-pairs ----------
#define WCR 128
#define WCC 64
#define WH  6
#define WTR 140
#define WTC 76
#define NPR 38
#define WP2 78
#define FTH 1024
#define PRPG 6
#define PNG 26

// ---------------- double fused kernel: 12 steps, halo 12, fp16-pair LDS -----
#define DCR 128                // core rows
#define DCC 64                 // core cols
#define DH  12                 // halo (12 fused steps)
#define DTR 152                // region rows
#define DTC 88                 // region cols = 44 pairs
#define DNP 44                 // column pairs
#define DLP 45                 // LDS row pitch in u32 (odd -> bank spread)
#define DTH 1024
#define DRPG 7                 // owned rows per thread
#define DNG 23                 // row groups (23*7 = 161 >= 150 interior rows)

// v_fma_mix_f32 with x in f32 (single kernel): acc += w(f32) * t.f16[sel].
#define FMAMIX_LO(acc, wv, hv) \
    asm("v_fma_mix_f32 %0, %1, %2, %0 op_sel:[0,0,0] op_sel_hi:[0,1,0]" \
        : "+v"(acc) : "v"(wv), "v"(hv))
#define FMAMIX_HI(acc, wv, hv) \
    asm("v_fma_mix_f32 %0, %1, %2, %0 op_sel:[0,1,0] op_sel_hi:[0,1,0]" \
        : "+v"(acc) : "v"(wv), "v"(hv))

// v_fma_mix_f32 with BOTH operands packed fp16 (double kernel, r20 proven).
#define FMIX_LL(acc, xv, tv) \
    asm("v_fma_mix_f32 %0, %1, %2, %0 op_sel:[0,0,0] op_sel_hi:[1,1,0]" \
        : "+v"(acc) : "v"(xv), "v"(tv))
#define FMIX_LH(acc, xv, tv) \
    asm("v_fma_mix_f32 %0, %1, %2, %0 op_sel:[0,1,0] op_sel_hi:[1,1,0]" \
        : "+v"(acc) : "v"(xv), "v"(tv))
#define FMIX_HL(acc, xv, tv) \
    asm("v_fma_mix_f32 %0, %1, %2, %0 op_sel:[1,0,0] op_sel_hi:[1,1,0]" \
        : "+v"(acc) : "v"(xv), "v"(tv))
#define FMIX_HH(acc, xv, tv) \
    asm("v_fma_mix_f32 %0, %1, %2, %0 op_sel:[1,1,0] op_sel_hi:[1,1,0]" \
        : "+v"(acc) : "v"(xv), "v"(tv))

__device__ __forceinline__ float hi_half_f32(unsigned h) {
    __half2 hh = *(__half2*)&h;
    return __half2float(__high2half(hh));
}
__device__ __forceinline__ unsigned pack2(float a, float b) {
    __half2 h = __floats2half2_rn(a, b);
    return *(unsigned*)&h;
}

// ---------------------------------------------------------------------------
// Kernel 1 (r17 proven): o-outer conv, 1 px/thread, contiguous weight loads.
// ---------------------------------------------------------------------------
__global__ __launch_bounds__(CTH2)
void conv_step0_kernel(const float* __restrict__ x,
                       const float* __restrict__ Wu,
                       const float* __restrict__ bu,
                       __half2* __restrict__ T,
                       float* __restrict__ out) {
    __shared__ float sX[4][CR][CP];

    int bx  = blockIdx.x;
    int b   = bx >> 10;
    int rem = bx & 1023;
    int by  = rem >> 5;
    int bc  = rem & 31;
    int i0  = by * CT;
    int j0  = bc * CT;

    const float* xb = x + ((size_t)b * Td + 12) * HWc;
    int tid = threadIdx.x;

    for (int idx = tid; idx < 4 * CR * CR; idx += CTH2) {
        int ch = idx / (CR * CR);
        int r2 = idx - ch * (CR * CR);
        int r  = r2 / CR;
        int c  = r2 - r * CR;
        int gi = i0 + r - 1, gj = j0 + c - 1;
        float v = 0.0f;
        if ((unsigned)gi < (unsigned)Hd && (unsigned)gj < (unsigned)Wd)
            v = xb[(size_t)ch * HWc + gi * Wd + gj];
        sX[ch][r][c] = v;
    }
    __syncthreads();

    int tx = tid & 15;
    int ty = tid >> 4;

    float xf[36];
    #pragma unroll
    for (int ch = 0; ch < 4; ++ch)
        #pragma unroll
        for (int kh = 0; kh < 3; ++kh)
            #pragma unroll
            for (int kw = 0; kw < 3; ++kw)
                xf[(ch * 3 + kh) * 3 + kw] = sX[ch][ty + kh][tx + kw];

    int gi = i0 + ty;
    int gj = j0 + tx;
    size_t pix = (size_t)gi * Wd + gj;
    __half2* Tb = T + (size_t)b * 5 * HWc;

    float o0 = 0.0f;
    float accPrev = 0.0f;
    #pragma unroll
    for (int o = 0; o < 10; ++o) {
        const float* wo = Wu + o * 36;
        float acc = bu[o];
        #pragma unroll
        for (int z = 0; z < 36; ++z)
            acc += xf[z] * wo[z];

        if (o < 9)
            o0 += xf[(3 * 3 + (o % 3)) * 3 + (o / 3)] * acc;
        else
            o0 += acc;

        if (o & 1) {
            __half2 h = __floats2half2_rn(accPrev, acc);
            *(unsigned*)(Tb + (size_t)(o >> 1) * HWc + pix) = *(unsigned*)&h;
        }
        accPrev = acc;
    }

    out[(size_t)b * Td * HWc + pix] = o0;
}

// ---------------------------------------------------------------------------
// Kernel 2 (DOUBLE): TWO scan iterations = 12 fused stencil steps, fp16-pair
// LDS state (r20-proven step body), region 152x88 (44 pairs), core 128x64,
// halo 12. At s=6 the valid band (distance>=6 from ring: rows/cols
// [6,145]x[6,81]) contains the core [12,139]x[12,74] -> store frame t to
// global (f32, pre-rounding) in addition to the LDS write. s=12 stores frame
// t+1 directly. Ring never written; contamination <=1 px/step. Out-of-image
// px forced 0 each step. 256 blocks = 1/CU. LDS 2 x 27.3 KB.
// ---------------------------------------------------------------------------
__global__ __launch_bounds__(DTH, 2)
void fused12_pk_kernel(const float* __restrict__ xin,   // out slot t-1 base
                       const __half2* __restrict__ T,
                       float* __restrict__ xmid,        // out slot t   base
                       float* __restrict__ xout) {      // out slot t+1 base
    __shared__ unsigned sA2[DTR * DLP];   // 27.4 KB
    __shared__ unsigned sB2[DTR * DLP];

    int tile = blockIdx.x;          // 256 = 8 b * 4 tr * 8 tc
    int b  = tile >> 5;
    int tr = (tile >> 3) & 3;
    int tc = tile & 7;
    int ri = tr * DCR - DH;
    int rj = tc * DCC - DH;         // even

    const float* xb = xin + (size_t)b * Td * HWc;
    const __half2* Tb = T + (size_t)b * 5 * HWc;
    float* obm = xmid + (size_t)b * Td * HWc;
    float* obo = xout + (size_t)b * Td * HWc;
    int tid = threadIdx.x;

    // Stage sA2 (packed pairs; pairs never straddle the image edge).
    for (int idx = tid; idx < DTR * DNP; idx += DTH) {
        int r = idx / DNP, u = idx - r * DNP;
        int gi = ri + r, gj0 = rj + 2 * u;
        unsigned v = 0u;
        if ((unsigned)gi < (unsigned)Hd && (unsigned)gj0 < (unsigned)Wd) {
            float2 f = *(const float2*)(xb + gi * Wd + gj0);
            v = pack2(f.x, f.y);
        }
        sA2[r * DLP + u] = v;
    }
    // Zero sB2's ring: rows 0/151 fully; pairs 0 and 43 every row.
    for (int idx = tid; idx < 2 * DNP; idx += DTH) {
        int r = (idx < DNP) ? 0 : (DTR - 1);
        int u = (idx < DNP) ? idx : idx - DNP;
        sB2[r * DLP + u] = 0u;
    }
    for (int idx = tid; idx < 2 * DTR; idx += DTH) {
        int r = (idx < DTR) ? idx : idx - DTR;
        int u = (idx < DTR) ? 0 : (DNP - 1);
        sB2[r * DLP + u] = 0u;
    }

    int g = tid / DNP;              // row group (0..22 active)
    int u = tid - g * DNP;          // pair index 0..43
    bool active = (g < DNG);
    int rs = 1 + g * DRPG;          // first owned row (1..155; rows >150 masked)
    int gj0 = rj + 2 * u;
    bool pairin = (unsigned)gj0 < (unsigned)Wd;
    int uL = (u == 0) ? 0 : u - 1;  // clamped; feeds masked outputs only
    int uR = (u == DNP - 1) ? (DNP - 1) : u + 1;

    // T coefs: uint2 = both pixels' half2 per plane per row.
    unsigned tA[DRPG][5], tB[DRPG][5];
    #pragma unroll
    for (int jj = 0; jj < DRPG; ++jj) {
        int r  = rs + jj;
        int gi = ri + r;
        bool ok = active && (r <= DTR - 2) && ((unsigned)gi < (unsigned)Hd) && pairin;
        #pragma unroll
        for (int q = 0; q < 5; ++q) {
            uint2 pk; pk.x = 0u; pk.y = 0u;
            if (ok) pk = *(const uint2*)(Tb + (size_t)q * HWc + gi * Wd + gj0);
            tA[jj][q] = pk.x;
            tB[jj][q] = pk.y;
        }
    }
    __syncthreads();

    unsigned* cur = sA2;
    unsigned* nxt = sB2;

    #pragma unroll
    for (int s = 1; s <= 12; ++s) {
        if (active) {
            int base = (rs - 1) * DLP;
            unsigned Ap = cur[base + uL], Bp = cur[base + u], Cp = cur[base + uR];
            base += DLP;
            unsigned Ac = cur[base + uL], Bc = cur[base + u], Cc = cur[base + uR];
            #pragma unroll
            for (int jj = 0; jj < DRPG; ++jj) {
                int r  = rs + jj;
                int rn = (r + 1 <= DTR - 1) ? (r + 1) : (DTR - 1);
                int bn = rn * DLP;
                unsigned An = cur[bn + uL], Bn = cur[bn + u], Cn = cur[bn + uR];

                // k = dj*3+di multiplies x[r+di-1][c+dj-1] (r20-verified taps).
                float a0 = hi_half_f32(tA[jj][4]);     // T9
                FMIX_HL(a0, Ap, tA[jj][0]);            // k0
                FMIX_HH(a0, Ac, tA[jj][0]);            // k1
                FMIX_HL(a0, An, tA[jj][1]);            // k2
                FMIX_LH(a0, Bp, tA[jj][1]);            // k3
                FMIX_LL(a0, Bc, tA[jj][2]);            // k4
                FMIX_LH(a0, Bn, tA[jj][2]);            // k5
                FMIX_HL(a0, Bp, tA[jj][3]);            // k6
                FMIX_HH(a0, Bc, tA[jj][3]);            // k7
                FMIX_HL(a0, Bn, tA[jj][4]);            // k8
                float a1 = hi_half_f32(tB[jj][4]);     // T9
                FMIX_LL(a1, Bp, tB[jj][0]);            // k0
                FMIX_LH(a1, Bc, tB[jj][0]);            // k1
                FMIX_LL(a1, Bn, tB[jj][1]);            // k2
                FMIX_HH(a1, Bp, tB[jj][1]);            // k3
                FMIX_HL(a1, Bc, tB[jj][2]);            // k4
                FMIX_HH(a1, Bn, tB[jj][2]);            // k5
                FMIX_LL(a1, Cp, tB[jj][3]);            // k6
                FMIX_LH(a1, Cc, tB[jj][3]);            // k7
                FMIX_LL(a1, Cn, tB[jj][4]);            // k8

                if ((s & 1) == 0) {
                    a0 = 1.0f / (1.0f + __expf(-a0));
                    a1 = 1.0f / (1.0f + __expf(-a1));
                }

                int gi = ri + r;
                bool inimg = ((unsigned)gi < (unsigned)Hd) && pairin;
                float v0 = inimg ? a0 : 0.0f;
                float v1 = inimg ? a1 : 0.0f;

                bool corepx = (u >= DH / 2) && (u <= (DTC - 2 - DH) / 2) &&
                              (r >= DH) && (r <= DTR - 1 - DH);
                if (s < 12) {
                    if (r <= DTR - 2) {
                        int cell = r * DLP + u;
                        if (u >= 1 && u <= DNP - 2) {
                            nxt[cell] = pack2(v0, v1);
                        } else if (u == 0) {
                            __half h1 = __float2half_rn(v1);
                            ((unsigned short*)nxt)[cell * 2 + 1] =
                                *(unsigned short*)&h1;
                        } else {
                            __half h0 = __float2half_rn(v0);
                            ((unsigned short*)nxt)[cell * 2] =
                                *(unsigned short*)&h0;
                        }
                    }
                    if (s == 6 && corepx) {
                        float2 st; st.x = v0; st.y = v1;
                        *(float2*)(obm + gi * Wd + gj0) = st;  // frame t
                    }
                } else {
                    if (corepx) {
                        float2 st; st.x = v0; st.y = v1;
                        *(float2*)(obo + gi * Wd + gj0) = st;  // frame t+1
                    }
                }

                Ap = Ac; Bp = Bc; Cp = Cc;
                Ac = An; Bc = Bn; Cc = Cn;
            }
        }
        if (s < 12) {
            __syncthreads();
            unsigned* tmp = cur; cur = nxt; nxt = tmp;
        }
    }
}

// ---------------------------------------------------------------------------
// Kernel 3 (r22 proven single): 6 steps, fp32 col-pair LDS state.
// ---------------------------------------------------------------------------
__global__ __launch_bounds__(FTH, 2)
void fused6_pair32_kernel(const float* __restrict__ xin,
                          const __half2* __restrict__ T,
                          float* __restrict__ xout) {
    __shared__ __align__(16) float sA[WTR * WP2];
    __shared__ __align__(16) float sB[WTR * WP2];

    int tile = blockIdx.x;
    int b  = tile >> 5;
    int tr = (tile >> 3) & 3;
    int tc = tile & 7;
    int ri = tr * WCR - WH;
    int rj = tc * WCC - WH;

    const float* xb = xin + (size_t)b * Td * HWc;
    const __half2* Tb = T + (size_t)b * 5 * HWc;
    float* ob = xout + (size_t)b * Td * HWc;
    int tid = threadIdx.x;

    for (int idx = tid; idx < WTR * NPR; idx += FTH) {
        int r = idx / NPR, u = idx - r * NPR;
        int gi = ri + r, gj0 = rj + 2 * u;
        float v0 = 0.0f, v1 = 0.0f;
        if ((unsigned)gi < (unsigned)Hd && (unsigned)gj0 < (unsigned)Wd) {
            float2 f = *(const float2*)(xb + gi * Wd + gj0);
            v0 = f.x; v1 = f.y;
        }
        float2 st; st.x = v0; st.y = v1;
        *(float2*)&sA[r * WP2 + 2 * u] = st;
    }
    for (int idx = tid; idx < 2 * WTC; idx += FTH) {
        int r = (idx < WTC) ? 0 : (WTR - 1);
        int c = (idx < WTC) ? idx : idx - WTC;
        sB[r * WP2 + c] = 0.0f;
    }
    for (int idx = tid; idx < 2 * WTR; idx += FTH) {
        int r = (idx < WTR) ? idx : idx - WTR;
        int c = (idx < WTR) ? 0 : (WTC - 1);
        sB[r * WP2 + c] = 0.0f;
    }

    int g = tid / NPR;
    int u = tid - g * NPR;
    bool active = (g < PNG);
    int rs = 1 + g * PRPG;
    int c0 = 2 * u;
    int gj0 = rj + c0;
    bool pairin = (unsigned)gj0 < (unsigned)Wd;
    int offL = (u == 0) ? 0 : (c0 - 1);
    int offR = (u == NPR - 1) ? (WTC - 1) : (c0 + 2);

    unsigned tA[PRPG][5], tB[PRPG][5];
    #pragma unroll
    for (int jj = 0; jj < PRPG; ++jj) {
        int r  = rs + jj;
        int gi = ri + r;
        bool ok = active && (r <= WTR - 2) && ((unsigned)gi < (unsigned)Hd) && pairin;
        #pragma unroll
        for (int q = 0; q < 5; ++q) {
            uint2 pk; pk.x = 0u; pk.y = 0u;
            if (ok) pk = *(const uint2*)(Tb + (size_t)q * HWc + gi * Wd + gj0);
            tA[jj][q] = pk.x;
            tB[jj][q] = pk.y;
        }
    }
    __syncthreads();

    float* cur = sA;
    float* nxt = sB;

    #pragma unroll
    for (int s = 1; s <= 6; ++s) {
        if (active) {
            int base = (rs - 1) * WP2;
            float  Lp = cur[base + offL];
            float2 Mp = *(const float2*)&cur[base + c0];
            float  Rp = cur[base + offR];
            base += WP2;
            float  Lc = cur[base + offL];
            float2 Mc = *(const float2*)&cur[base + c0];
            float  Rc = cur[base + offR];
            #pragma unroll
            for (int jj = 0; jj < PRPG; ++jj) {
                int r  = rs + jj;
                int rn = (r + 1 <= WTR - 1) ? (r + 1) : (WTR - 1);
                int bn = rn * WP2;
                float  Ln = cur[bn + offL];
                float2 Mn = *(const float2*)&cur[bn + c0];
                float  Rn = cur[bn + offR];

                float a0 = hi_half_f32(tA[jj][4]);
                FMAMIX_LO(a0, Lp,   tA[jj][0]);
                FMAMIX_HI(a0, Lc,   tA[jj][0]);
                FMAMIX_LO(a0, Ln,   tA[jj][1]);
                FMAMIX_HI(a0, Mp.x, tA[jj][1]);
                FMAMIX_LO(a0, Mc.x, tA[jj][2]);
                FMAMIX_HI(a0, Mn.x, tA[jj][2]);
                FMAMIX_LO(a0, Mp.y, tA[jj][3]);
                FMAMIX_HI(a0, Mc.y, tA[jj][3]);
                FMAMIX_LO(a0, Mn.y, tA[jj][4]);
                float a1 = hi_half_f32(tB[jj][4]);
                FMAMIX_LO(a1, Mp.x, tB[jj][0]);
                FMAMIX_HI(a1, Mc.x, tB[jj][0]);
                FMAMIX_LO(a1, Mn.x, tB[jj][1]);
                FMAMIX_HI(a1, Mp.y, tB[jj][1]);
                FMAMIX_LO(a1, Mc.y, tB[jj][2]);
                FMAMIX_HI(a1, Mn.y, tB[jj][2]);
                FMAMIX_LO(a1, Rp,   tB[jj][3]);
                FMAMIX_HI(a1, Rc,   tB[jj][3]);
                FMAMIX_LO(a1, Rn,   tB[jj][4]);

                if ((s & 1) == 0) {
                    a0 = 1.0f / (1.0f + __expf(-a0));
                    a1 = 1.0f / (1.0f + __expf(-a1));
                }

                int gi = ri + r;
                bool inimg = ((unsigned)gi < (unsigned)Hd) && pairin;
                float v0 = inimg ? a0 : 0.0f;
                float v1 = inimg ? a1 : 0.0f;

                if (s < 6) {
                    if (r <= WTR - 2) {
                        if (u >= 1 && u <= NPR - 2) {
                            float2 st; st.x = v0; st.y = v1;
                            *(float2*)&nxt[r * WP2 + c0] = st;
                        } else if (u == 0) {
                            nxt[r * WP2 + 1] = v1;
                        } else {
                            nxt[r * WP2 + WTC - 2] = v0;
                        }
                    }
                } else {
                    if (u >= WH / 2 && u <= (WTC - 2 - WH) / 2 &&
                        r >= WH && r <= WTR - 1 - WH) {
                        float2 st; st.x = v0; st.y = v1;
                        *(float2*)(ob + gi * Wd + gj0) = st;
                    }
                }

                Lp = Lc; Mp = Mc; Rp = Rc;
                Lc = Ln; Mc = Mn; Rc = Rn;
            }
        }
        if (s < 6) {
            __syncthreads();
            float* tmp = cur; cur = nxt; nxt = tmp;
        }
    }
}

// ---------------------------------------------------------------------------
// Workspace: T only (B*5*H*W half2 = 40 MB).
// ---------------------------------------------------------------------------
extern "C" void kernel_launch(void* const* d_in, const int* in_sizes, int n_in,
                              void* d_out, int out_size, void* d_ws, size_t ws_size,
                              hipStream_t stream) {
    const float* x  = (const float*)d_in[0];
    const float* Wu = (const float*)d_in[1];
    const float* bu = (const float*)d_in[2];
    float* out = (float*)d_out;
    __half2* T = (__half2*)d_ws;

    conv_step0_kernel<<<8192, CTH2, 0, stream>>>(x, Wu, bu, T, out);

    // Spill gate on the double kernel (r16-proven host query, capture-safe).
    hipFuncAttributes attr;
    hipError_t qe = hipFuncGetAttributes(&attr, (const void*)fused12_pk_kernel);
    bool useDouble = (qe == hipSuccess) && (attr.localSizeBytes == 0);

    if (useDouble) {
        for (int t = 1; t + 1 < Td; t += 2)   // pairs (1,2),(3,4),...,(13,14)
            fused12_pk_kernel<<<256, DTH, 0, stream>>>(
                out + (size_t)(t - 1) * HWc, T,
                out + (size_t)t * HWc, out + (size_t)(t + 1) * HWc);
        fused6_pair32_kernel<<<256, FTH, 0, stream>>>(      // t = 15
            out + (size_t)14 * HWc, T, out + (size_t)15 * HWc);
    } else {
        for (int t = 1; t < Td; ++t)
            fused6_pair32_kernel<<<256, FTH, 0, stream>>>(
                out + (size_t)(t - 1) * HWc, T, out + (size_t)t * HWc);
    }
}

// Round 24
// 480.134 us; speedup vs baseline: 1.0030x; 1.0030x over previous
//
#include <hip/hip_runtime.h>
#include <hip/hip_fp16.h>
#include <math.h>

// Problem constants: B=8, Tt=16, C=1, H=W=512, 4 in-channels, 10 T-planes.
#define Bd 8
#define Td 16
#define Hd 512
#define Wd 512
#define HWc (Hd * Wd)          // 262144
#define NPIX (Bd * HWc)        // 2,097,152

// ---------------- conv tiling: 16x16 tile, 1 px/thread, 256 threads ----------
#define CT  16
#define CR  18
#define CP  20
#define CTH2 256

// ---------------- big fused kernel (r22 proven): 128x64 core -----------------
#define WCR 128
#define WCC 64
#define WH  6
#define WTR 140
#define WTC 76
#define NPR 38
#define WP2 78
#define FTH 1024
#define PRPG 6
#define PNG 26

// ---------------- small fused kernel: 64x64 core, 512 thr, 2 blocks/CU -------
#define SCR 64
#define SCC 64
#define SH  6
#define STR 76
#define STC 76
#define SNP 38
#define SP2 78
#define STH 512
#define SRPG 6
#define SNG 13                 // 13*6 = 78 >= 74 interior rows

// v_fma_mix_f32: acc(f32) += w(f32) * h.lo/h.hi(f16) in ONE instruction.
#define FMAMIX_LO(acc, wv, hv) \
    asm("v_fma_mix_f32 %0, %1, %2, %0 op_sel:[0,0,0] op_sel_hi:[0,1,0]" \
        : "+v"(acc) : "v"(wv), "v"(hv))
#define FMAMIX_HI(acc, wv, hv) \
    asm("v_fma_mix_f32 %0, %1, %2, %0 op_sel:[0,1,0] op_sel_hi:[0,1,0]" \
        : "+v"(acc) : "v"(wv), "v"(hv))

__device__ __forceinline__ float hi_half_f32(unsigned h) {
    __half2 hh = *(__half2*)&h;
    return __half2float(__high2half(hh));
}

// ---------------------------------------------------------------------------
// Kernel 1 (r17 proven): o-outer conv, 1 px/thread, contiguous weight loads.
// T = conv2d(x[:,-4:,0],W)+b fused with xt0 -> out[:,0].
// T stored as half2 pairs: plane q holds (T[2q], T[2q+1]); layout (B,5,H,W).
// ---------------------------------------------------------------------------
__global__ __launch_bounds__(CTH2)
void conv_step0_kernel(const float* __restrict__ x,
                       const float* __restrict__ Wu,
                       const float* __restrict__ bu,
                       __half2* __restrict__ T,
                       float* __restrict__ out) {
    __shared__ float sX[4][CR][CP];

    int bx  = blockIdx.x;
    int b   = bx >> 10;
    int rem = bx & 1023;
    int by  = rem >> 5;
    int bc  = rem & 31;
    int i0  = by * CT;
    int j0  = bc * CT;

    const float* xb = x + ((size_t)b * Td + 12) * HWc;
    int tid = threadIdx.x;

    for (int idx = tid; idx < 4 * CR * CR; idx += CTH2) {
        int ch = idx / (CR * CR);
        int r2 = idx - ch * (CR * CR);
        int r  = r2 / CR;
        int c  = r2 - r * CR;
        int gi = i0 + r - 1, gj = j0 + c - 1;
        float v = 0.0f;
        if ((unsigned)gi < (unsigned)Hd && (unsigned)gj < (unsigned)Wd)
            v = xb[(size_t)ch * HWc + gi * Wd + gj];
        sX[ch][r][c] = v;
    }
    __syncthreads();

    int tx = tid & 15;
    int ty = tid >> 4;

    float xf[36];
    #pragma unroll
    for (int ch = 0; ch < 4; ++ch)
        #pragma unroll
        for (int kh = 0; kh < 3; ++kh)
            #pragma unroll
            for (int kw = 0; kw < 3; ++kw)
                xf[(ch * 3 + kh) * 3 + kw] = sX[ch][ty + kh][tx + kw];

    int gi = i0 + ty;
    int gj = j0 + tx;
    size_t pix = (size_t)gi * Wd + gj;
    __half2* Tb = T + (size_t)b * 5 * HWc;

    float o0 = 0.0f;
    float accPrev = 0.0f;
    #pragma unroll
    for (int o = 0; o < 10; ++o) {
        const float* wo = Wu + o * 36;
        float acc = bu[o];
        #pragma unroll
        for (int z = 0; z < 36; ++z)
            acc += xf[z] * wo[z];

        if (o < 9)
            o0 += xf[(3 * 3 + (o % 3)) * 3 + (o / 3)] * acc;
        else
            o0 += acc;

        if (o & 1) {
            __half2 h = __floats2half2_rn(accPrev, acc);
            *(unsigned*)(Tb + (size_t)(o >> 1) * HWc + pix) = *(unsigned*)&h;
        }
        accPrev = acc;
    }

    out[(size_t)b * Td * HWc + pix] = o0;
}

// ---------------------------------------------------------------------------
// Kernel 2 (preferred): SMALL fused kernel — r22's pair32 step body at 64x64
// core (region 76x76), 512 threads, 512 blocks -> 2 blocks/CU (if VGPR<=128;
// host occupancy gate verifies) so block B's T-load overlaps block A's steps.
// fp32 LDS state, 2-col-pair ownership, fma_mix taps, ring never written,
// halo 6, direct global store at s=6.
// ---------------------------------------------------------------------------
__global__ __launch_bounds__(STH, 2)
void fused6_small_kernel(const float* __restrict__ xin,   // out slot t-1 base
                         const __half2* __restrict__ T,
                         float* __restrict__ xout) {      // out slot t base
    __shared__ __align__(16) float sA[STR * SP2];   // 23.7 KB
    __shared__ __align__(16) float sB[STR * SP2];

    int tile = blockIdx.x;          // 512 = 8 b * 8 tr * 8 tc
    int b  = tile >> 6;
    int tr = (tile >> 3) & 7;
    int tc = tile & 7;
    int ri = tr * SCR - SH;
    int rj = tc * SCC - SH;         // even

    const float* xb = xin + (size_t)b * Td * HWc;
    const __half2* Tb = T + (size_t)b * 5 * HWc;
    float* ob = xout + (size_t)b * Td * HWc;
    int tid = threadIdx.x;

    // Stage sA by pairs (zeros outside image; pairs never straddle the edge).
    for (int idx = tid; idx < STR * SNP; idx += STH) {
        int r = idx / SNP, u = idx - r * SNP;
        int gi = ri + r, gj0 = rj + 2 * u;
        float v0 = 0.0f, v1 = 0.0f;
        if ((unsigned)gi < (unsigned)Hd && (unsigned)gj0 < (unsigned)Wd) {
            float2 f = *(const float2*)(xb + gi * Wd + gj0);
            v0 = f.x; v1 = f.y;
        }
        float2 st; st.x = v0; st.y = v1;
        *(float2*)&sA[r * SP2 + 2 * u] = st;
    }
    // Zero sB's ring.
    for (int idx = tid; idx < 2 * STC; idx += STH) {
        int r = (idx < STC) ? 0 : (STR - 1);
        int c = (idx < STC) ? idx : idx - STC;
        sB[r * SP2 + c] = 0.0f;
    }
    for (int idx = tid; idx < 2 * STR; idx += STH) {
        int r = (idx < STR) ? idx : idx - STR;
        int c = (idx < STR) ? 0 : (STC - 1);
        sB[r * SP2 + c] = 0.0f;
    }

    int g = tid / SNP;              // row group (0..12 active)
    int u = tid - g * SNP;          // pair index 0..37
    bool active = (g < SNG);
    int rs = 1 + g * SRPG;          // first owned row (1..73; rows >74 masked)
    int c0 = 2 * u;
    int gj0 = rj + c0;
    bool pairin = (unsigned)gj0 < (unsigned)Wd;
    int offL = (u == 0) ? 0 : (c0 - 1);            // clamped; feeds ring only
    int offR = (u == SNP - 1) ? (STC - 1) : (c0 + 2);

    unsigned tA[SRPG][5], tB[SRPG][5];
    #pragma unroll
    for (int jj = 0; jj < SRPG; ++jj) {
        int r  = rs + jj;
        int gi = ri + r;
        bool ok = active && (r <= STR - 2) && ((unsigned)gi < (unsigned)Hd) && pairin;
        #pragma unroll
        for (int q = 0; q < 5; ++q) {
            uint2 pk; pk.x = 0u; pk.y = 0u;
            if (ok) pk = *(const uint2*)(Tb + (size_t)q * HWc + gi * Wd + gj0);
            tA[jj][q] = pk.x;
            tB[jj][q] = pk.y;
        }
    }
    __syncthreads();

    float* cur = sA;
    float* nxt = sB;

    #pragma unroll
    for (int s = 1; s <= 6; ++s) {
        if (active) {
            int base = (rs - 1) * SP2;
            float  Lp = cur[base + offL];
            float2 Mp = *(const float2*)&cur[base + c0];
            float  Rp = cur[base + offR];
            base += SP2;
            float  Lc = cur[base + offL];
            float2 Mc = *(const float2*)&cur[base + c0];
            float  Rc = cur[base + offR];
            #pragma unroll
            for (int jj = 0; jj < SRPG; ++jj) {
                int r  = rs + jj;
                int rn = (r + 1 <= STR - 1) ? (r + 1) : (STR - 1);
                int bn = rn * SP2;
                float  Ln = cur[bn + offL];
                float2 Mn = *(const float2*)&cur[bn + c0];
                float  Rn = cur[bn + offR];

                // k = dj*3+di multiplies x[r+di-1][c+dj-1].
                float a0 = hi_half_f32(tA[jj][4]);     // T9
                FMAMIX_LO(a0, Lp,   tA[jj][0]);
                FMAMIX_HI(a0, Lc,   tA[jj][0]);
                FMAMIX_LO(a0, Ln,   tA[jj][1]);
                FMAMIX_HI(a0, Mp.x, tA[jj][1]);
                FMAMIX_LO(a0, Mc.x, tA[jj][2]);
                FMAMIX_HI(a0, Mn.x, tA[jj][2]);
                FMAMIX_LO(a0, Mp.y, tA[jj][3]);
                FMAMIX_HI(a0, Mc.y, tA[jj][3]);
                FMAMIX_LO(a0, Mn.y, tA[jj][4]);
                float a1 = hi_half_f32(tB[jj][4]);     // T9
                FMAMIX_LO(a1, Mp.x, tB[jj][0]);
                FMAMIX_HI(a1, Mc.x, tB[jj][0]);
                FMAMIX_LO(a1, Mn.x, tB[jj][1]);
                FMAMIX_HI(a1, Mp.y, tB[jj][1]);
                FMAMIX_LO(a1, Mc.y, tB[jj][2]);
                FMAMIX_HI(a1, Mn.y, tB[jj][2]);
                FMAMIX_LO(a1, Rp,   tB[jj][3]);
                FMAMIX_HI(a1, Rc,   tB[jj][3]);
                FMAMIX_LO(a1, Rn,   tB[jj][4]);

                if ((s & 1) == 0) {
                    a0 = 1.0f / (1.0f + __expf(-a0));
                    a1 = 1.0f / (1.0f + __expf(-a1));
                }

                int gi = ri + r;
                bool inimg = ((unsigned)gi < (unsigned)Hd) && pairin;
                float v0 = inimg ? a0 : 0.0f;
                float v1 = inimg ? a1 : 0.0f;

                if (s < 6) {
                    if (r <= STR - 2) {
                        if (u >= 1 && u <= SNP - 2) {
                            float2 st; st.x = v0; st.y = v1;
                            *(float2*)&nxt[r * SP2 + c0] = st;
                        } else if (u == 0) {
                            nxt[r * SP2 + 1] = v1;
                        } else {
                            nxt[r * SP2 + STC - 2] = v0;
                        }
                    }
                } else {
                    if (u >= SH / 2 && u <= (STC - 2 - SH) / 2 &&
                        r >= SH && r <= STR - 1 - SH) {
                        float2 st; st.x = v0; st.y = v1;
                        *(float2*)(ob + gi * Wd + gj0) = st;
                    }
                }

                Lp = Lc; Mp = Mc; Rp = Rc;
                Lc = Ln; Mc = Mn; Rc = Rn;
            }
        }
        if (s < 6) {
            __syncthreads();
            float* tmp = cur; cur = nxt; nxt = tmp;
        }
    }
}

// ---------------------------------------------------------------------------
// Kernel 3 (fallback, r22 proven): 128x64 core, 1024 threads, 256 blocks.
// ---------------------------------------------------------------------------
__global__ __launch_bounds__(FTH, 2)
void fused6_pair32_kernel(const float* __restrict__ xin,
                          const __half2* __restrict__ T,
                          float* __restrict__ xout) {
    __shared__ __align__(16) float sA[WTR * WP2];
    __shared__ __align__(16) float sB[WTR * WP2];

    int tile = blockIdx.x;
    int b  = tile >> 5;
    int tr = (tile >> 3) & 3;
    int tc = tile & 7;
    int ri = tr * WCR - WH;
    int rj = tc * WCC - WH;

    const float* xb = xin + (size_t)b * Td * HWc;
    const __half2* Tb = T + (size_t)b * 5 * HWc;
    float* ob = xout + (size_t)b * Td * HWc;
    int tid = threadIdx.x;

    for (int idx = tid; idx < WTR * NPR; idx += FTH) {
        int r = idx / NPR, u = idx - r * NPR;
        int gi = ri + r, gj0 = rj + 2 * u;
        float v0 = 0.0f, v1 = 0.0f;
        if ((unsigned)gi < (unsigned)Hd && (unsigned)gj0 < (unsigned)Wd) {
            float2 f = *(const float2*)(xb + gi * Wd + gj0);
            v0 = f.x; v1 = f.y;
        }
        float2 st; st.x = v0; st.y = v1;
        *(float2*)&sA[r * WP2 + 2 * u] = st;
    }
    for (int idx = tid; idx < 2 * WTC; idx += FTH) {
        int r = (idx < WTC) ? 0 : (WTR - 1);
        int c = (idx < WTC) ? idx : idx - WTC;
        sB[r * WP2 + c] = 0.0f;
    }
    for (int idx = tid; idx < 2 * WTR; idx += FTH) {
        int r = (idx < WTR) ? idx : idx - WTR;
        int c = (idx < WTR) ? 0 : (WTC - 1);
        sB[r * WP2 + c] = 0.0f;
    }

    int g = tid / NPR;
    int u = tid - g * NPR;
    bool active = (g < PNG);
    int rs = 1 + g * PRPG;
    int c0 = 2 * u;
    int gj0 = rj + c0;
    bool pairin = (unsigned)gj0 < (unsigned)Wd;
    int offL = (u == 0) ? 0 : (c0 - 1);
    int offR = (u == NPR - 1) ? (WTC - 1) : (c0 + 2);

    unsigned tA[PRPG][5], tB[PRPG][5];
    #pragma unroll
    for (int jj = 0; jj < PRPG; ++jj) {
        int r  = rs + jj;
        int gi = ri + r;
        bool ok = active && (r <= WTR - 2) && ((unsigned)gi < (unsigned)Hd) && pairin;
        #pragma unroll
        for (int q = 0; q < 5; ++q) {
            uint2 pk; pk.x = 0u; pk.y = 0u;
            if (ok) pk = *(const uint2*)(Tb + (size_t)q * HWc + gi * Wd + gj0);
            tA[jj][q] = pk.x;
            tB[jj][q] = pk.y;
        }
    }
    __syncthreads();

    float* cur = sA;
    float* nxt = sB;

    #pragma unroll
    for (int s = 1; s <= 6; ++s) {
        if (active) {
            int base = (rs - 1) * WP2;
            float  Lp = cur[base + offL];
            float2 Mp = *(const float2*)&cur[base + c0];
            float  Rp = cur[base + offR];
            base += WP2;
            float  Lc = cur[base + offL];
            float2 Mc = *(const float2*)&cur[base + c0];
            float  Rc = cur[base + offR];
            #pragma unroll
            for (int jj = 0; jj < PRPG; ++jj) {
                int r  = rs + jj;
                int rn = (r + 1 <= WTR - 1) ? (r + 1) : (WTR - 1);
                int bn = rn * WP2;
                float  Ln = cur[bn + offL];
                float2 Mn = *(const float2*)&cur[bn + c0];
                float  Rn = cur[bn + offR];

                float a0 = hi_half_f32(tA[jj][4]);
                FMAMIX_LO(a0, Lp,   tA[jj][0]);
                FMAMIX_HI(a0, Lc,   tA[jj][0]);
                FMAMIX_LO(a0, Ln,   tA[jj][1]);
                FMAMIX_HI(a0, Mp.x, tA[jj][1]);
                FMAMIX_LO(a0, Mc.x, tA[jj][2]);
                FMAMIX_HI(a0, Mn.x, tA[jj][2]);
                FMAMIX_LO(a0, Mp.y, tA[jj][3]);
                FMAMIX_HI(a0, Mc.y, tA[jj][3]);
                FMAMIX_LO(a0, Mn.y, tA[jj][4]);
                float a1 = hi_half_f32(tB[jj][4]);
                FMAMIX_LO(a1, Mp.x, tB[jj][0]);
                FMAMIX_HI(a1, Mc.x, tB[jj][0]);
                FMAMIX_LO(a1, Mn.x, tB[jj][1]);
                FMAMIX_HI(a1, Mp.y, tB[jj][1]);
                FMAMIX_LO(a1, Mc.y, tB[jj][2]);
                FMAMIX_HI(a1, Mn.y, tB[jj][2]);
                FMAMIX_LO(a1, Rp,   tB[jj][3]);
                FMAMIX_HI(a1, Rc,   tB[jj][3]);
                FMAMIX_LO(a1, Rn,   tB[jj][4]);

                if ((s & 1) == 0) {
                    a0 = 1.0f / (1.0f + __expf(-a0));
                    a1 = 1.0f / (1.0f + __expf(-a1));
                }

                int gi = ri + r;
                bool inimg = ((unsigned)gi < (unsigned)Hd) && pairin;
                float v0 = inimg ? a0 : 0.0f;
                float v1 = inimg ? a1 : 0.0f;

                if (s < 6) {
                    if (r <= WTR - 2) {
                        if (u >= 1 && u <= NPR - 2) {
                            float2 st; st.x = v0; st.y = v1;
                            *(float2*)&nxt[r * WP2 + c0] = st;
                        } else if (u == 0) {
                            nxt[r * WP2 + 1] = v1;
                        } else {
                            nxt[r * WP2 + WTC - 2] = v0;
                        }
                    }
                } else {
                    if (u >= WH / 2 && u <= (WTC - 2 - WH) / 2 &&
                        r >= WH && r <= WTR - 1 - WH) {
                        float2 st; st.x = v0; st.y = v1;
                        *(float2*)(ob + gi * Wd + gj0) = st;
                    }
                }

                Lp = Lc; Mp = Mc; Rp = Rc;
                Lc = Ln; Mc = Mn; Rc = Rn;
            }
        }
        if (s < 6) {
            __syncthreads();
            float* tmp = cur; cur = nxt; nxt = tmp;
        }
    }
}

// ---------------------------------------------------------------------------
// Workspace: T only (B*5*H*W half2 = 40 MB).
// ---------------------------------------------------------------------------
extern "C" void kernel_launch(void* const* d_in, const int* in_sizes, int n_in,
                              void* d_out, int out_size, void* d_ws, size_t ws_size,
                              hipStream_t stream) {
    const float* x  = (const float*)d_in[0];
    const float* Wu = (const float*)d_in[1];
    const float* bu = (const float*)d_in[2];
    float* out = (float*)d_out;
    __half2* T = (__half2*)d_ws;

    conv_step0_kernel<<<8192, CTH2, 0, stream>>>(x, Wu, bu, T, out);

    // Occupancy gate: take the small-tile path only if >= 2 blocks/CU fit
    // (detects both VGPR overflow and LDS pressure). Host query, capture-safe,
    // deterministic per device/compile.
    int nb = 0;
    hipError_t qe = hipOccupancyMaxActiveBlocksPerMultiprocessor(
        &nb, fused6_small_kernel, STH, 0);
    bool useSmall = (qe == hipSuccess) && (nb >= 2);

    if (useSmall) {
        for (int t = 1; t < Td; ++t)
            fused6_small_kernel<<<512, STH, 0, stream>>>(
                out + (size_t)(t - 1) * HWc, T, out + (size_t)t * HWc);
    } else {
        for (int t = 1; t < Td; ++t)
            fused6_pair32_kernel<<<256, FTH, 0, stream>>>(
                out + (size_t)(t - 1) * HWc, T, out + (size_t)t * HWc);
    }
}

// Round 25
// 479.105 us; speedup vs baseline: 1.0051x; 1.0021x over previous
//
#include <hip/hip_runtime.h>
#include <hip/hip_fp16.h>
#include <math.h>

// Problem constants: B=8, Tt=16, C=1, H=W=512, 4 in-channels, 10 T-planes.
#define Bd 8
#define Td 16
#define Hd 512
#define Wd 512
#define HWc (Hd * Wd)          // 262144
#define NPIX (Bd * HWc)        // 2,097,152

// ---------------- conv tiling: 32x16 tile, 2 px/thread (1x2), 256 threads ----
#define C2TW 32                // tile cols
#define C2TH 16                // tile rows
#define C2RW 34                // region cols
#define C2RH 18                // region rows
#define C2P  36                // LDS row pitch (even words)
#define C2THR 256

// ---------------- fused kernel (r22 proven): 128x64 core, fp32 col-pairs -----
#define WCR 128
#define WCC 64
#define WH  6
#define WTR 140
#define WTC 76
#define NPR 38
#define WP2 78
#define FTH 1024
#define PRPG 6
#define PNG 26

// v_fma_mix_f32: acc(f32) += w(f32) * h.lo/h.hi(f16) in ONE instruction.
#define FMAMIX_LO(acc, wv, hv) \
    asm("v_fma_mix_f32 %0, %1, %2, %0 op_sel:[0,0,0] op_sel_hi:[0,1,0]" \
        : "+v"(acc) : "v"(wv), "v"(hv))
#define FMAMIX_HI(acc, wv, hv) \
    asm("v_fma_mix_f32 %0, %1, %2, %0 op_sel:[0,1,0] op_sel_hi:[0,1,0]" \
        : "+v"(acc) : "v"(wv), "v"(hv))

__device__ __forceinline__ float hi_half_f32(unsigned h) {
    __half2 hh = *(__half2*)&h;
    return __half2float(__high2half(hh));
}

// ---------------------------------------------------------------------------
// Kernel 1: o-outer conv at 2 px/thread (horizontal pair). Each output
// channel o reads 36 CONTIGUOUS weights (batched s_load) feeding 2 FMAs per
// weight. T = conv2d(x[:,-4:,0],W)+b fused with xt0 -> out[:,0].
// T stored as half2 pairs: plane q holds (T[2q], T[2q+1]); layout (B,5,H,W).
// ---------------------------------------------------------------------------
__global__ __launch_bounds__(C2THR)
void conv_step0_kernel(const float* __restrict__ x,
                       const float* __restrict__ Wu,
                       const float* __restrict__ bu,
                       __half2* __restrict__ T,
                       float* __restrict__ out) {
    __shared__ __align__(16) float sX[4][C2RH][C2P];   // 10.4 KB

    int bx  = blockIdx.x;               // 4096 = 8 b * 32 row-bands * 16 col-bands
    int b   = bx >> 9;
    int rem = bx & 511;
    int by  = rem >> 4;                 // row band 0..31 (16 rows)
    int bc  = rem & 15;                 // col band 0..15 (32 cols)
    int i0  = by * C2TH;
    int j0  = bc * C2TW;

    const float* xb = x + ((size_t)b * Td + 12) * HWc;   // channel c -> slice 12+c
    int tid = threadIdx.x;

    // Stage the 4-channel 18x34 region (zeros outside image).
    for (int idx = tid; idx < 4 * C2RH * C2RW; idx += C2THR) {
        int ch = idx / (C2RH * C2RW);
        int r2 = idx - ch * (C2RH * C2RW);
        int r  = r2 / C2RW;
        int c  = r2 - r * C2RW;
        int gi = i0 + r - 1, gj = j0 + c - 1;
        float v = 0.0f;
        if ((unsigned)gi < (unsigned)Hd && (unsigned)gj < (unsigned)Wd)
            v = xb[(size_t)ch * HWc + gi * Wd + gj];
        sX[ch][r][c] = v;
    }
    __syncthreads();

    int tx = tid & 15;                  // pair: tile cols 2tx, 2tx+1
    int ty = tid >> 4;                  // tile row 0..15

    // Window: 4 ch x 3 rows x 4 cols (region rows ty..ty+2, cols 2tx..2tx+3).
    float xw[4][3][4];
    #pragma unroll
    for (int ch = 0; ch < 4; ++ch)
        #pragma unroll
        for (int kh = 0; kh < 3; ++kh) {
            const float* rp = &sX[ch][ty + kh][2 * tx];
            float2 a  = *(const float2*)rp;
            float2 b2 = *(const float2*)(rp + 2);
            xw[ch][kh][0] = a.x;  xw[ch][kh][1] = a.y;
            xw[ch][kh][2] = b2.x; xw[ch][kh][3] = b2.y;
        }

    int gi = i0 + ty;
    int gj0 = j0 + 2 * tx;              // even
    size_t pix = (size_t)gi * Wd + gj0;
    __half2* Tb = T + (size_t)b * 5 * HWc;

    float o0 = 0.0f, o1 = 0.0f;         // step0 accumulators (px0, px1)
    float ap0 = 0.0f, ap1 = 0.0f;       // previous-o accumulators
    #pragma unroll
    for (int o = 0; o < 10; ++o) {
        const float* wo = Wu + o * 36;  // 36 contiguous weights -> batched s_load
        float acc0 = bu[o], acc1 = acc0;
        #pragma unroll
        for (int ch = 0; ch < 4; ++ch)
            #pragma unroll
            for (int kh = 0; kh < 3; ++kh)
                #pragma unroll
                for (int kw = 0; kw < 3; ++kw) {
                    float wt = wo[(ch * 3 + kh) * 3 + kw];
                    acc0 += xw[ch][kh][kw]     * wt;
                    acc1 += xw[ch][kh][kw + 1] * wt;
                }

        // step0 inline: k = dj*3+di multiplies x15[i+di-1, j+dj-1];
        // channel-3 window supplies the taps (px1 shifted one col right).
        if (o < 9) {
            int di = o % 3, dj = o / 3;
            o0 += xw[3][di][dj]     * acc0;
            o1 += xw[3][di][dj + 1] * acc1;
        } else {
            o0 += acc0;
            o1 += acc1;
        }

        if (o & 1) {
            __half2 h0 = __floats2half2_rn(ap0, acc0);
            __half2 h1 = __floats2half2_rn(ap1, acc1);
            uint2 pk;
            pk.x = *(unsigned*)&h0;
            pk.y = *(unsigned*)&h1;
            *(uint2*)(Tb + (size_t)(o >> 1) * HWc + pix) = pk;
        }
        ap0 = acc0; ap1 = acc1;
    }

    float2 ov; ov.x = o0; ov.y = o1;
    *(float2*)(out + (size_t)b * Td * HWc + pix) = ov;
}

// ---------------------------------------------------------------------------
// Kernel 2 (r22 proven): one scan-body iteration = 6 fused stencil steps,
// 128x64 core (region 140x76, pitch 78), fp32 LDS state, 2-col-pair
// ownership (3 LDS reads / 2 px), fma_mix taps, ring never written,
// halo 6, direct global store at s=6. 256 blocks = 1/CU.
// ---------------------------------------------------------------------------
__global__ __launch_bounds__(FTH, 2)
void fused6_pair32_kernel(const float* __restrict__ xin,   // out slot t-1 base
                          const __half2* __restrict__ T,
                          float* __restrict__ xout) {      // out slot t base
    __shared__ __align__(16) float sA[WTR * WP2];   // 43.7 KB
    __shared__ __align__(16) float sB[WTR * WP2];

    int tile = blockIdx.x;          // 256 = 8 b * 4 tr * 8 tc
    int b  = tile >> 5;
    int tr = (tile >> 3) & 3;
    int tc = tile & 7;
    int ri = tr * WCR - WH;
    int rj = tc * WCC - WH;         // even

    const float* xb = xin + (size_t)b * Td * HWc;
    const __half2* Tb = T + (size_t)b * 5 * HWc;
    float* ob = xout + (size_t)b * Td * HWc;
    int tid = threadIdx.x;

    // Stage sA by pairs (zeros outside image; pairs never straddle the edge).
    for (int idx = tid; idx < WTR * NPR; idx += FTH) {
        int r = idx / NPR, u = idx - r * NPR;
        int gi = ri + r, gj0 = rj + 2 * u;
        float v0 = 0.0f, v1 = 0.0f;
        if ((unsigned)gi < (unsigned)Hd && (unsigned)gj0 < (unsigned)Wd) {
            float2 f = *(const float2*)(xb + gi * Wd + gj0);
            v0 = f.x; v1 = f.y;
        }
        float2 st; st.x = v0; st.y = v1;
        *(float2*)&sA[r * WP2 + 2 * u] = st;
    }
    // Zero sB's ring (never written by the step loop; interior fully
    // rewritten each step before being read).
    for (int idx = tid; idx < 2 * WTC; idx += FTH) {
        int r = (idx < WTC) ? 0 : (WTR - 1);
        int c = (idx < WTC) ? idx : idx - WTC;
        sB[r * WP2 + c] = 0.0f;
    }
    for (int idx = tid; idx < 2 * WTR; idx += FTH) {
        int r = (idx < WTR) ? idx : idx - WTR;
        int c = (idx < WTR) ? 0 : (WTC - 1);
        sB[r * WP2 + c] = 0.0f;
    }

    int g = tid / NPR;              // row group (0..25 active)
    int u = tid - g * NPR;          // pair index 0..37
    bool active = (g < PNG);
    int rs = 1 + g * PRPG;          // first owned row (1..151; rows >138 masked)
    int c0 = 2 * u;
    int gj0 = rj + c0;
    bool pairin = (unsigned)gj0 < (unsigned)Wd;
    int offL = (u == 0) ? 0 : (c0 - 1);            // clamped; feeds ring only
    int offR = (u == NPR - 1) ? (WTC - 1) : (c0 + 2);

    unsigned tA[PRPG][5], tB[PRPG][5];
    #pragma unroll
    for (int jj = 0; jj < PRPG; ++jj) {
        int r  = rs + jj;
        int gi = ri + r;
        bool ok = active && (r <= WTR - 2) && ((unsigned)gi < (unsigned)Hd) && pairin;
        #pragma unroll
        for (int q = 0; q < 5; ++q) {
            uint2 pk; pk.x = 0u; pk.y = 0u;
            if (ok) pk = *(const uint2*)(Tb + (size_t)q * HWc + gi * Wd + gj0);
            tA[jj][q] = pk.x;
            tB[jj][q] = pk.y;
        }
    }
    __syncthreads();

    float* cur = sA;
    float* nxt = sB;

    #pragma unroll
    for (int s = 1; s <= 6; ++s) {
        if (active) {
            int base = (rs - 1) * WP2;
            float  Lp = cur[base + offL];
            float2 Mp = *(const float2*)&cur[base + c0];
            float  Rp = cur[base + offR];
            base += WP2;
            float  Lc = cur[base + offL];
            float2 Mc = *(const float2*)&cur[base + c0];
            float  Rc = cur[base + offR];
            #pragma unroll
            for (int jj = 0; jj < PRPG; ++jj) {
                int r  = rs + jj;
                int rn = (r + 1 <= WTR - 1) ? (r + 1) : (WTR - 1);
                int bn = rn * WP2;
                float  Ln = cur[bn + offL];
                float2 Mn = *(const float2*)&cur[bn + c0];
                float  Rn = cur[bn + offR];

                // k = dj*3+di multiplies x[r+di-1][c+dj-1].
                float a0 = hi_half_f32(tA[jj][4]);     // T9
                FMAMIX_LO(a0, Lp,   tA[jj][0]);
                FMAMIX_HI(a0, Lc,   tA[jj][0]);
                FMAMIX_LO(a0, Ln,   tA[jj][1]);
                FMAMIX_HI(a0, Mp.x, tA[jj][1]);
                FMAMIX_LO(a0, Mc.x, tA[jj][2]);
                FMAMIX_HI(a0, Mn.x, tA[jj][2]);
                FMAMIX_LO(a0, Mp.y, tA[jj][3]);
                FMAMIX_HI(a0, Mc.y, tA[jj][3]);
                FMAMIX_LO(a0, Mn.y, tA[jj][4]);
                float a1 = hi_half_f32(tB[jj][4]);     // T9
                FMAMIX_LO(a1, Mp.x, tB[jj][0]);
                FMAMIX_HI(a1, Mc.x, tB[jj][0]);
                FMAMIX_LO(a1, Mn.x, tB[jj][1]);
                FMAMIX_HI(a1, Mp.y, tB[jj][1]);
                FMAMIX_LO(a1, Mc.y, tB[jj][2]);
                FMAMIX_HI(a1, Mn.y, tB[jj][2]);
                FMAMIX_LO(a1, Rp,   tB[jj][3]);
                FMAMIX_HI(a1, Rc,   tB[jj][3]);
                FMAMIX_LO(a1, Rn,   tB[jj][4]);

                if ((s & 1) == 0) {
                    a0 = 1.0f / (1.0f + __expf(-a0));
                    a1 = 1.0f / (1.0f + __expf(-a1));
                }

                int gi = ri + r;
                bool inimg = ((unsigned)gi < (unsigned)Hd) && pairin;
                float v0 = inimg ? a0 : 0.0f;
                float v1 = inimg ? a1 : 0.0f;

                if (s < 6) {
                    if (r <= WTR - 2) {
                        if (u >= 1 && u <= NPR - 2) {
                            float2 st; st.x = v0; st.y = v1;
                            *(float2*)&nxt[r * WP2 + c0] = st;
                        } else if (u == 0) {
                            nxt[r * WP2 + 1] = v1;
                        } else {
                            nxt[r * WP2 + WTC - 2] = v0;
                        }
                    }
                } else {
                    if (u >= WH / 2 && u <= (WTC - 2 - WH) / 2 &&
                        r >= WH && r <= WTR - 1 - WH) {
                        float2 st; st.x = v0; st.y = v1;
                        *(float2*)(ob + gi * Wd + gj0) = st;
                    }
                }

                Lp = Lc; Mp = Mc; Rp = Rc;
                Lc = Ln; Mc = Mn; Rc = Rn;
            }
        }
        if (s < 6) {
            __syncthreads();
            float* tmp = cur; cur = nxt; nxt = tmp;
        }
    }
}

// ---------------------------------------------------------------------------
// Workspace: T only (B*5*H*W half2 = 40 MB).
// ---------------------------------------------------------------------------
extern "C" void kernel_launch(void* const* d_in, const int* in_sizes, int n_in,
                              void* d_out, int out_size, void* d_ws, size_t ws_size,
                              hipStream_t stream) {
    const float* x  = (const float*)d_in[0];
    const float* Wu = (const float*)d_in[1];
    const float* bu = (const float*)d_in[2];
    float* out = (float*)d_out;
    __half2* T = (__half2*)d_ws;

    conv_step0_kernel<<<4096, C2THR, 0, stream>>>(x, Wu, bu, T, out);

    for (int t = 1; t < Td; ++t)
        fused6_pair32_kernel<<<256, FTH, 0, stream>>>(out + (size_t)(t - 1) * HWc, T,
                                                      out + (size_t)t * HWc);
}